// Round 1
// baseline (834.661 us; speedup 1.0000x reference)
//
#include <hip/hip_runtime.h>
#include <hip/hip_bf16.h>

typedef __attribute__((ext_vector_type(8))) short short8;      // 8 x bf16 (4 VGPR)
typedef __attribute__((ext_vector_type(4))) float f32x4;       // MFMA acc
typedef __attribute__((ext_vector_type(4))) unsigned int u32x4;

static __device__ __forceinline__ unsigned short f2b(float f) {
  unsigned int u = __builtin_bit_cast(unsigned int, f);
  u = (u + 0x7fffu + ((u >> 16) & 1u)) >> 16;   // RNE
  return (unsigned short)u;
}
static __device__ __forceinline__ float b2f(unsigned short h) {
  unsigned int u = ((unsigned int)h) << 16;
  return __builtin_bit_cast(float, u);
}

// ---------------- edge dtype detection ----------------
// int64 edges: values < 2^17 so every odd 32-bit word (high half) is 0.
// int32 edges: odd words are random node ids in [0,100000) -> ~never all zero.
__global__ void detect_kernel(const int* __restrict__ ew, int* __restrict__ flag) {
  if (threadIdx.x == 0 && blockIdx.x == 0) {
    int z = 0;
#pragma unroll
    for (int i = 1; i < 32; i += 2) z |= ew[i];
    *flag = (z == 0) ? 1 : 0;   // 1 => int64
  }
}

// ---------------- degree (incl. self-loop) ----------------
__global__ __launch_bounds__(256) void init_deg_kernel(int* __restrict__ deg, int n) {
  int i = blockIdx.x * 256 + threadIdx.x;
  if (i < n) deg[i] = 1;   // self-loop
}

__global__ __launch_bounds__(256) void deg_kernel(const int* __restrict__ ew, int ne,
                                                  const int* __restrict__ flag,
                                                  int* __restrict__ deg) {
  int e = blockIdx.x * 256 + threadIdx.x;
  if (e >= ne) return;
  const int is64 = *flag;
  int d = is64 ? ew[(size_t)2 * ne + 2 * (size_t)e] : ew[(size_t)ne + e];
  atomicAdd(&deg[d], 1);
}

// ---------------- exclusive scan of (deg-1) -> rowptr, cursor, dinv ----------------
__global__ __launch_bounds__(1024) void scan_kernel(int* __restrict__ deg_cursor,
                                                    int* __restrict__ rowptr,
                                                    float* __restrict__ dinv, int n) {
  __shared__ int part[1024];
  const int t = threadIdx.x;
  const int chunk = (n + 1023) >> 10;
  const int lo = t * chunk;
  const int hi = lo + chunk < n ? lo + chunk : n;
  int s = 0;
  for (int i = lo; i < hi; ++i) s += deg_cursor[i] - 1;
  part[t] = s;
  __syncthreads();
  for (int off = 1; off < 1024; off <<= 1) {
    int v = 0;
    if (t >= off) v = part[t - off];
    __syncthreads();
    part[t] += v;
    __syncthreads();
  }
  int run = (t == 0) ? 0 : part[t - 1];
  for (int i = lo; i < hi; ++i) {
    int d = deg_cursor[i];
    rowptr[i] = run;
    deg_cursor[i] = run;              // becomes the scatter cursor
    dinv[i] = rsqrtf((float)d);       // d >= 1 always
    run += d - 1;
  }
  if (hi == n && lo < n) rowptr[n] = run;
}

// ---------------- scatter edges into CSR (by dst) ----------------
__global__ __launch_bounds__(256) void scatter_kernel(const int* __restrict__ ew, int ne,
                                                      const int* __restrict__ flag,
                                                      int* __restrict__ cursor,
                                                      int* __restrict__ csr_src) {
  int e = blockIdx.x * 256 + threadIdx.x;
  if (e >= ne) return;
  const int is64 = *flag;
  int s, d;
  if (is64) {
    s = ew[2 * (size_t)e];
    d = ew[(size_t)2 * ne + 2 * (size_t)e];
  } else {
    s = ew[e];
    d = ew[(size_t)ne + e];
  }
  int pos = atomicAdd(&cursor[d], 1);
  csr_src[pos] = s;
}

// ---------------- W_gcn^T cast to bf16: Wt[c][k], c<64, k<512 ----------------
__global__ __launch_bounds__(256) void wt_kernel(const float* __restrict__ Wg,
                                                 unsigned short* __restrict__ Wt) {
  int t = blockIdx.x * 256 + threadIdx.x;   // 32768 total
  int k = t >> 6, c = t & 63;
  Wt[c * 512 + k] = f2b(Wg[t]);             // Wg[k*64 + c]
}

// ---------------- h = bf16(x) @ bf16(W) via MFMA, h stored bf16 ----------------
// block = 256 thr = 4 waves; wave -> 32 rows x 64 cols; block -> 128 rows.
__global__ __launch_bounds__(256) void gemm_kernel(const float* __restrict__ x,
                                                   const unsigned short* __restrict__ Wt,
                                                   unsigned short* __restrict__ hbf,
                                                   int nnodes) {
  __shared__ unsigned short Bt[64][40];   // 32 k padded to 40 (bank-conflict-free b128)
  const int tid = threadIdx.x;
  const int lane = tid & 63;
  const int wv = tid >> 6;
  const int l15 = lane & 15;
  const int hi = lane >> 4;               // 0..3
  const int rowbase = blockIdx.x * 128 + wv * 32;

  f32x4 acc[2][4] = {};

  for (int kc = 0; kc < 16; ++kc) {
    const int k0 = kc * 32;
    {   // stage B chunk: Wt[c][k0..k0+32) -> Bt[c][0..32)
      int c = tid >> 2, seg = tid & 3;
      u32x4 v = *reinterpret_cast<const u32x4*>(Wt + c * 512 + k0 + seg * 8);
      *reinterpret_cast<u32x4*>(&Bt[c][seg * 8]) = v;
    }
    __syncthreads();

    short8 afrag[2];
#pragma unroll
    for (int i = 0; i < 2; ++i) {
      int row = rowbase + i * 16 + l15;
      row = row < nnodes ? row : nnodes - 1;
      const float* p = x + (size_t)row * 512 + k0 + hi * 8;
      f32x4 f0 = *reinterpret_cast<const f32x4*>(p);
      f32x4 f1 = *reinterpret_cast<const f32x4*>(p + 4);
      short8 a;
      a[0] = (short)f2b(f0[0]); a[1] = (short)f2b(f0[1]);
      a[2] = (short)f2b(f0[2]); a[3] = (short)f2b(f0[3]);
      a[4] = (short)f2b(f1[0]); a[5] = (short)f2b(f1[1]);
      a[6] = (short)f2b(f1[2]); a[7] = (short)f2b(f1[3]);
      afrag[i] = a;
    }
#pragma unroll
    for (int j = 0; j < 4; ++j) {
      short8 b = *reinterpret_cast<const short8*>(&Bt[j * 16 + l15][hi * 8]);
      acc[0][j] = __builtin_amdgcn_mfma_f32_16x16x32_bf16(afrag[0], b, acc[0][j], 0, 0, 0);
      acc[1][j] = __builtin_amdgcn_mfma_f32_16x16x32_bf16(afrag[1], b, acc[1][j], 0, 0, 0);
    }
    __syncthreads();
  }

  // C/D layout (m89-verified): col = lane&15, row = (lane>>4)*4 + reg
#pragma unroll
  for (int i = 0; i < 2; ++i)
#pragma unroll
    for (int j = 0; j < 4; ++j)
#pragma unroll
      for (int r = 0; r < 4; ++r) {
        int row = rowbase + i * 16 + hi * 4 + r;
        if (row < nnodes) hbf[(size_t)row * 64 + j * 16 + l15] = f2b(acc[i][j][r]);
      }
}

// ---------------- aggregate (gather by CSR) + bias + relu + classifier ----------------
// one wave per node; lane = hidden feature
__global__ __launch_bounds__(256) void agg_kernel(const unsigned short* __restrict__ hbf,
                                                  const int* __restrict__ rowptr,
                                                  const int* __restrict__ csr_src,
                                                  const float* __restrict__ dinv,
                                                  const float* __restrict__ b_gcn,
                                                  const float* __restrict__ W_cls,
                                                  const float* __restrict__ b_cls,
                                                  float* __restrict__ out, int n) {
  const int lane = threadIdx.x & 63;
  const int node = blockIdx.x * 4 + (threadIdx.x >> 6);
  if (node >= n) return;

  const float dn = dinv[node];
  float inner = 0.f;                                  // sum h[s]*dinv[s]
  const int e0 = rowptr[node], e1 = rowptr[node + 1];
  int e = e0;
  for (; e + 4 <= e1; e += 4) {
    int s0 = csr_src[e], s1 = csr_src[e + 1], s2 = csr_src[e + 2], s3 = csr_src[e + 3];
    float w0 = dinv[s0], w1 = dinv[s1], w2 = dinv[s2], w3 = dinv[s3];
    float v0 = b2f(hbf[(size_t)s0 * 64 + lane]);
    float v1 = b2f(hbf[(size_t)s1 * 64 + lane]);
    float v2 = b2f(hbf[(size_t)s2 * 64 + lane]);
    float v3 = b2f(hbf[(size_t)s3 * 64 + lane]);
    inner = fmaf(v0, w0, inner);
    inner = fmaf(v1, w1, inner);
    inner = fmaf(v2, w2, inner);
    inner = fmaf(v3, w3, inner);
  }
  for (; e < e1; ++e) {
    int s = csr_src[e];
    inner = fmaf(b2f(hbf[(size_t)s * 64 + lane]), dinv[s], inner);
  }
  float self = b2f(hbf[(size_t)node * 64 + lane]) * dn;   // self-loop: h[n]*dn^2
  float h2 = fmaf(dn, inner + self, b_gcn[lane]);
  h2 = h2 > 0.f ? h2 : 0.f;

  float p[7];
#pragma unroll
  for (int c = 0; c < 7; ++c) p[c] = h2 * W_cls[lane * 7 + c];
#pragma unroll
  for (int off = 32; off; off >>= 1) {
#pragma unroll
    for (int c = 0; c < 7; ++c) p[c] += __shfl_xor(p[c], off, 64);
  }
  if (lane == 0) {
    float* o = out + (size_t)node * 7;
#pragma unroll
    for (int c = 0; c < 7; ++c) o[c] = p[c] + b_cls[c];
  }
}

extern "C" void kernel_launch(void* const* d_in, const int* in_sizes, int n_in,
                              void* d_out, int out_size, void* d_ws, size_t ws_size,
                              hipStream_t stream) {
  const float* x = (const float*)d_in[0];
  const int* ew = (const int*)d_in[1];          // edge_index as 32-bit words
  const float* W_gcn = (const float*)d_in[2];
  const float* b_gcn = (const float*)d_in[3];
  const float* W_cls = (const float*)d_in[4];
  const float* b_cls = (const float*)d_in[5];
  float* out = (float*)d_out;

  const int N = in_sizes[0] / 512;              // 100000
  const int NE = in_sizes[1] / 2;               // 3200000

  // workspace carve-out (256B aligned)
  size_t off = 0;
  auto take = [&](size_t b) { size_t o = off; off += (b + 255) & ~(size_t)255; return o; };
  char* ws = (char*)d_ws;
  int* flag            = (int*)(ws + take(sizeof(int)));
  unsigned short* Wt   = (unsigned short*)(ws + take((size_t)512 * 64 * 2));
  int* cursor          = (int*)(ws + take((size_t)N * 4));       // deg -> cursor
  int* rowptr          = (int*)(ws + take(((size_t)N + 1) * 4));
  float* dinv          = (float*)(ws + take((size_t)N * 4));
  unsigned short* hbf  = (unsigned short*)(ws + take((size_t)N * 64 * 2));
  int* csr_src         = (int*)(ws + take((size_t)NE * 4));
  (void)ws_size;

  const int nbN = (N + 255) / 256;
  const int nbE = (NE + 255) / 256;

  detect_kernel<<<1, 64, 0, stream>>>(ew, flag);
  init_deg_kernel<<<nbN, 256, 0, stream>>>(cursor, N);
  deg_kernel<<<nbE, 256, 0, stream>>>(ew, NE, flag, cursor);
  scan_kernel<<<1, 1024, 0, stream>>>(cursor, rowptr, dinv, N);
  scatter_kernel<<<nbE, 256, 0, stream>>>(ew, NE, flag, cursor, csr_src);
  wt_kernel<<<128, 256, 0, stream>>>(W_gcn, Wt);
  gemm_kernel<<<(N + 127) / 128, 256, 0, stream>>>(x, Wt, hbf, N);
  agg_kernel<<<(N + 3) / 4, 256, 0, stream>>>(hbf, rowptr, csr_src, dinv,
                                              b_gcn, W_cls, b_cls, out, N);
}